// Round 4
// baseline (33518.683 us; speedup 1.0000x reference)
//
#include <hip/hip_runtime.h>

// Seq2Seq summarizer forward. External tensors f32 (runtime-probed, bf16 also
// handled); internal compute bf16 MFMA + f32 state. ~110 MB ws.
// R4: encoder fused into ONE persistent kernel (64 co-resident blocks,
// register-resident weights, epoch barrier in ws) replacing 1024 dispatches.

#define DI __device__ __forceinline__

constexpr int BATCH = 32;
constexpr int TS = 1024;
constexpr int TG = 64;
constexpr int HID = 512;
constexpr int GD = 2048;     // 4*HID
constexpr int EDIM = 256;
constexpr int SPECIAL = 4;
constexpr size_t OFF_H = (size_t)BATCH * TG * EDIM;         // h_all elem offset in d_out
constexpr size_t OFF_C = OFF_H + (size_t)BATCH * TG * HID;  // c_all elem offset

typedef __attribute__((ext_vector_type(8))) short bf16x8;
typedef __attribute__((ext_vector_type(4))) float f32x4;

DI float b2f(unsigned short u) {
  union { unsigned int i; float f; } v; v.i = ((unsigned int)u) << 16; return v.f;
}
DI unsigned short f2b(float f) {
  union { float f; unsigned int i; } v; v.f = f;
  unsigned int r = v.i + 0x7fffu + ((v.i >> 16) & 1u);
  return (unsigned short)(r >> 16);
}
DI float sigm(float x) { return 1.0f / (1.0f + expf(-x)); }
DI float ldf(const void* p, size_t i, int f32f) {
  return f32f ? ((const float*)p)[i] : b2f(((const unsigned short*)p)[i]);
}
DI void stf(void* p, size_t i, float v, int f32f) {
  if (f32f) ((float*)p)[i] = v; else ((unsigned short*)p)[i] = f2b(v);
}

// dtype probe: f32 N(0,1) words are "sane"; bf16 pairs read as f32 are wild.
__global__ void detect_k(const void* art, int* flag) {
  int tid = threadIdx.x;
  float x = ((const float*)art)[tid + 1024];
  float a = fabsf(x);
  int sane = (x == 0.0f) || (a > 1e-8f && a < 1e4f);
  unsigned long long m = __ballot(sane);
  __shared__ int cnt[4];
  if ((tid & 63) == 0) cnt[tid >> 6] = __popcll(m);
  __syncthreads();
  if (tid == 0) flag[0] = (cnt[0] + cnt[1] + cnt[2] + cnt[3] > 128) ? 1 : 0;
}

__global__ void fill_sig_k(unsigned short* o, int n) {
  int g = blockIdx.x * 256 + threadIdx.x;
  if (g < n) o[g] = 0x42F6;  // ws-too-small signature (~123)
}

// Pack W[GD][HID] -> MFMA B-frags, gate-interleaved per 16-hidden-unit block.
__global__ void pack_gate_k(const void* __restrict__ W,
                            unsigned short* __restrict__ pk, const int* dtf) {
  int f32f = dtf[0];
  int g = blockIdx.x * 256 + threadIdx.x;
  if (g >= (GD * HID) / 8) return;
  int lane = g & 63;
  int kk = (g >> 6) & 15;
  int tile = g >> 10;
  int p = tile * 16 + (lane & 15);
  int nloc = p & 63, blk = p >> 6;
  int orow = (nloc >> 4) * HID + blk * 16 + (nloc & 15);
  int k = kk * 32 + (lane >> 4) * 8;
  unsigned short tmp[8];
#pragma unroll
  for (int j = 0; j < 8; ++j) tmp[j] = f2b(ldf(W, (size_t)orow * HID + k + j, f32f));
  *(uint4*)(pk + (size_t)g * 8) = *(uint4*)tmp;
}

__global__ void pack_wm_k(const void* __restrict__ wm,
                          unsigned short* __restrict__ pk, const int* dtf) {
  int f32f = dtf[0];
  int g = blockIdx.x * 256 + threadIdx.x;
  if (g >= 32 * 32 * 64) return;
  int lane = g & 63;
  int kk = (g >> 6) & 31;
  int nt = g >> 11;
  int col = nt * 16 + (lane & 15);
  int kb = kk * 32 + (lane >> 4) * 8;
  unsigned short tmp[8];
#pragma unroll
  for (int j = 0; j < 8; ++j) tmp[j] = f2b(ldf(wm, (size_t)(kb + j) * HID + col, f32f));
  *(uint4*)(pk + (size_t)g * 8) = *(uint4*)tmp;
}

// ---------------------------------------------------------------------------
// Persistent bidirectional encoder. 64 blocks (32 fwd + 32 bwd), co-resident
// by construction (<= 256 CUs). Per-wave weights in VGPRs (128), c in regs,
// per-direction epoch barrier through ws for the h handoff.
// ---------------------------------------------------------------------------
__global__ __launch_bounds__(256) void enc_all_k(
    const void* __restrict__ article,
    unsigned short* __restrict__ outF, unsigned short* __restrict__ outB,
    const unsigned short* __restrict__ hIF, const unsigned short* __restrict__ hIB,
    float* __restrict__ cF, float* __restrict__ cB,
    const unsigned short* __restrict__ pkXF, const unsigned short* __restrict__ pkHF,
    const unsigned short* __restrict__ pkXB, const unsigned short* __restrict__ pkHB,
    const void* __restrict__ bF, const void* __restrict__ bB,
    int* __restrict__ bar, const int* dtf) {
  const int f32f = dtf[0];
  const int blk = blockIdx.x;
  const int dir = blk >> 5;
  const int blk16 = blk & 31;
  const int tid = threadIdx.x;
  const int lane = tid & 63;
  const int wv = tid >> 6;
  const int tile = blk16 * 4 + wv;

  __shared__ unsigned short lstage[BATCH * HID];  // 32 KB
  __shared__ float gbuf[BATCH * 68];              // 8.5 KB

  const unsigned short* pkX = dir ? pkXB : pkXF;
  const unsigned short* pkH = dir ? pkHB : pkHF;
  const void* bias = dir ? bB : bF;
  unsigned short* out = dir ? outB : outF;
  const unsigned short* hI = dir ? hIB : hIF;
  float* cg = dir ? cB : cF;
  int* cnt = bar + dir * 64;          // separate cache lines per direction

  // ---- weights -> VGPRs (this wave's n-tile, all K) ----
  bf16x8 wx[16], wh[16];
  {
    const unsigned short* px = pkX + ((size_t)tile * 16 * 64 + lane) * 8;
    const unsigned short* ph = pkH + ((size_t)tile * 16 * 64 + lane) * 8;
#pragma unroll
    for (int kk = 0; kk < 16; ++kk) {
      wx[kk] = *(const bf16x8*)(px + (size_t)kk * 64 * 8);
      wh[kk] = *(const bf16x8*)(ph + (size_t)kk * 64 * 8);
    }
  }
  // ---- c state -> registers (thread owns (b,jj) pairs idx0=tid, idx1=256+tid)
  const int jj0 = tid & 15, b0 = tid >> 4;          // idx0
  const int jj1 = (256 + tid) & 15, b1 = (256 + tid) >> 4;
  float c0 = cg[b0 * HID + blk16 * 16 + jj0];
  float c1 = cg[b1 * HID + blk16 * 16 + jj1];

  const int r0 = lane & 15;
  const int r1 = 16 + r0;
  const int kbb = (lane >> 4) * 8;
  const int nloc = wv * 16 + (lane & 15);
  const int orow = (nloc >> 4) * HID + blk16 * 16 + (nloc & 15);
  const float bv = ldf(bias, orow, f32f);

  for (int t = 0; t < TS; ++t) {
    const int tsrc = dir ? (TS - 1 - t) : t;
    // ---- stage x(tsrc) into LDS (f32->bf16 or bf16 passthrough) ----
#pragma unroll
    for (int it = 0; it < 8; ++it) {
      int ci = it * 256 + tid;
      int row = ci >> 6;
      int k8 = (ci & 63) << 3;
      unsigned off = (unsigned)(row * 1024 + ((k8 * 2) ^ ((row & 7) << 4)));
      if (f32f) {
        const float* s = (const float*)article + (size_t)tsrc * BATCH * HID +
                         (size_t)row * HID + k8;
        float4 u0 = *(const float4*)s;
        float4 u1 = *(const float4*)(s + 4);
        unsigned short tmp[8] = {f2b(u0.x), f2b(u0.y), f2b(u0.z), f2b(u0.w),
                                 f2b(u1.x), f2b(u1.y), f2b(u1.z), f2b(u1.w)};
        *(uint4*)((char*)lstage + off) = *(uint4*)tmp;
      } else {
        const unsigned short* s = (const unsigned short*)article +
                                  (size_t)tsrc * BATCH * HID + (size_t)row * HID + k8;
        *(uint4*)((char*)lstage + off) = *(const uint4*)s;
      }
    }
    __syncthreads();
    // ---- issue h(prev) loads early (hidden under x-MFMA) ----
    const unsigned short* hp =
        (t == 0) ? hI : out + (size_t)(tsrc + (dir ? 1 : -1)) * BATCH * HID;
    uint4 hreg[8];
#pragma unroll
    for (int it = 0; it < 8; ++it) {
      int ci = it * 256 + tid;
      int row = ci >> 6;
      int k8 = (ci & 63) << 3;
      hreg[it] = *(const uint4*)(hp + (size_t)row * HID + k8);
    }
    // ---- x pass ----
    f32x4 acc0 = {0.f, 0.f, 0.f, 0.f};
    f32x4 acc1 = {0.f, 0.f, 0.f, 0.f};
#pragma unroll
    for (int kk = 0; kk < 16; ++kk) {
      unsigned o0 = (unsigned)(r0 * 1024 + (((kk * 32 + kbb) * 2) ^ ((r0 & 7) << 4)));
      unsigned o1 = (unsigned)(r1 * 1024 + (((kk * 32 + kbb) * 2) ^ ((r0 & 7) << 4)));
      bf16x8 a0 = *(const bf16x8*)((const char*)lstage + o0);
      bf16x8 a1 = *(const bf16x8*)((const char*)lstage + o1);
      acc0 = __builtin_amdgcn_mfma_f32_16x16x32_bf16(a0, wx[kk], acc0, 0, 0, 0);
      acc1 = __builtin_amdgcn_mfma_f32_16x16x32_bf16(a1, wx[kk], acc1, 0, 0, 0);
    }
    __syncthreads();                  // x reads done before overwrite
    // ---- write h into LDS ----
#pragma unroll
    for (int it = 0; it < 8; ++it) {
      int ci = it * 256 + tid;
      int row = ci >> 6;
      int k8 = (ci & 63) << 3;
      unsigned off = (unsigned)(row * 1024 + ((k8 * 2) ^ ((row & 7) << 4)));
      *(uint4*)((char*)lstage + off) = hreg[it];
    }
    __syncthreads();
    // ---- h pass ----
#pragma unroll
    for (int kk = 0; kk < 16; ++kk) {
      unsigned o0 = (unsigned)(r0 * 1024 + (((kk * 32 + kbb) * 2) ^ ((r0 & 7) << 4)));
      unsigned o1 = (unsigned)(r1 * 1024 + (((kk * 32 + kbb) * 2) ^ ((r0 & 7) << 4)));
      bf16x8 a0 = *(const bf16x8*)((const char*)lstage + o0);
      bf16x8 a1 = *(const bf16x8*)((const char*)lstage + o1);
      acc0 = __builtin_amdgcn_mfma_f32_16x16x32_bf16(a0, wh[kk], acc0, 0, 0, 0);
      acc1 = __builtin_amdgcn_mfma_f32_16x16x32_bf16(a1, wh[kk], acc1, 0, 0, 0);
    }
#pragma unroll
    for (int r = 0; r < 4; ++r) {
      int brow = (lane >> 4) * 4 + r;
      gbuf[brow * 68 + nloc] = acc0[r] + bv;
      gbuf[(16 + brow) * 68 + nloc] = acc1[r] + bv;
    }
    __syncthreads();
    // ---- gates -> c,h update; store h slice ----
    unsigned short* hrow = out + (size_t)tsrc * BATCH * HID + blk16 * 16;
    {
      float gi = gbuf[b0 * 68 + jj0];
      float gf = gbuf[b0 * 68 + 16 + jj0];
      float gg = gbuf[b0 * 68 + 32 + jj0];
      float go = gbuf[b0 * 68 + 48 + jj0];
      float cn = sigm(gf) * c0 + sigm(gi) * tanhf(gg);
      c0 = cn;
      hrow[b0 * HID + jj0] = f2b(sigm(go) * tanhf(cn));
    }
    {
      float gi = gbuf[b1 * 68 + jj1];
      float gf = gbuf[b1 * 68 + 16 + jj1];
      float gg = gbuf[b1 * 68 + 32 + jj1];
      float go = gbuf[b1 * 68 + 48 + jj1];
      float cn = sigm(gf) * c1 + sigm(gi) * tanhf(gg);
      c1 = cn;
      hrow[b1 * HID + jj1] = f2b(sigm(go) * tanhf(cn));
    }
    // ---- per-direction epoch barrier (release h, wait for 32 arrivals) ----
    __threadfence();
    __syncthreads();
    if (tid == 0) {
      __hip_atomic_fetch_add(cnt, 1, __ATOMIC_RELEASE, __HIP_MEMORY_SCOPE_AGENT);
      const int target = 32 * (t + 1);
      while (__hip_atomic_load(cnt, __ATOMIC_RELAXED, __HIP_MEMORY_SCOPE_AGENT) < target)
        __builtin_amdgcn_s_sleep(16);
    }
    __syncthreads();
    __threadfence();                  // acquire: invalidate before reading peers' h
  }
  // ---- final c back to global (for mv_ff_k) ----
  cg[b0 * HID + blk16 * 16 + jj0] = c0;
  cg[b1 * HID + blk16 * 16 + jj1] = c1;
}

// LSTM cell (decoder path), per-block hidden slice: unchanged from R3.
template <bool EXTX>
DI void cell_block(const void* __restrict__ xg,
                   const unsigned short* __restrict__ hg,
                   const unsigned short* __restrict__ pkX,
                   const unsigned short* __restrict__ pkH,
                   const void* __restrict__ bias,
                   float* __restrict__ c,
                   unsigned short* __restrict__ hout,
                   void* dout, int step, int blk16, int f32f) {
  __shared__ unsigned short lstage[BATCH * HID];
  __shared__ float gbuf[BATCH * 68];
  const int tid = threadIdx.x;
  const int lane = tid & 63;
  const int wv = tid >> 6;
  const int tile = blk16 * 4 + wv;
  const int r0 = lane & 15;
  const int r1 = 16 + r0;
  const int kbb = (lane >> 4) * 8;
  f32x4 acc0 = {0.f, 0.f, 0.f, 0.f};
  f32x4 acc1 = {0.f, 0.f, 0.f, 0.f};

  for (int pass = 0; pass < 2; ++pass) {
    const unsigned short* pw = (pass ? pkH : pkX) + (size_t)tile * 16 * 64 * 8;
    if (pass) __syncthreads();
#pragma unroll
    for (int it = 0; it < 8; ++it) {
      int ci = it * 256 + tid;
      int row = ci >> 6;
      int k8 = (ci & 63) << 3;
      unsigned off = (unsigned)(row * 1024 + ((k8 * 2) ^ ((row & 7) << 4)));
      if (pass == 0 && EXTX && f32f) {
        const float* s = (const float*)xg + (size_t)row * HID + k8;
        float4 u0 = *(const float4*)s;
        float4 u1 = *(const float4*)(s + 4);
        unsigned short tmp[8] = {f2b(u0.x), f2b(u0.y), f2b(u0.z), f2b(u0.w),
                                 f2b(u1.x), f2b(u1.y), f2b(u1.z), f2b(u1.w)};
        *(uint4*)((char*)lstage + off) = *(uint4*)tmp;
      } else {
        const unsigned short* s =
            pass ? hg + (size_t)row * HID + k8
                 : (const unsigned short*)xg + (size_t)row * HID + k8;
        *(uint4*)((char*)lstage + off) = *(const uint4*)s;
      }
    }
    __syncthreads();
#pragma unroll
    for (int kk = 0; kk < 16; ++kk) {
      unsigned o0 = (unsigned)(r0 * 1024 + (((kk * 32 + kbb) * 2) ^ ((r0 & 7) << 4)));
      unsigned o1 = (unsigned)(r1 * 1024 + (((kk * 32 + kbb) * 2) ^ ((r0 & 7) << 4)));
      bf16x8 a0 = *(const bf16x8*)((const char*)lstage + o0);
      bf16x8 a1 = *(const bf16x8*)((const char*)lstage + o1);
      bf16x8 bb = *(const bf16x8*)(pw + (size_t)(kk * 64 + lane) * 8);
      acc0 = __builtin_amdgcn_mfma_f32_16x16x32_bf16(a0, bb, acc0, 0, 0, 0);
      acc1 = __builtin_amdgcn_mfma_f32_16x16x32_bf16(a1, bb, acc1, 0, 0, 0);
    }
  }
  const int nloc = wv * 16 + (lane & 15);
  const int orow = (nloc >> 4) * HID + blk16 * 16 + (nloc & 15);
  const float bv = ldf(bias, orow, f32f);
#pragma unroll
  for (int r = 0; r < 4; ++r) {
    int brow = (lane >> 4) * 4 + r;
    gbuf[brow * 68 + nloc] = acc0[r] + bv;
    gbuf[(16 + brow) * 68 + nloc] = acc1[r] + bv;
  }
  __syncthreads();
#pragma unroll
  for (int it = 0; it < 2; ++it) {
    int idx = it * 256 + tid;
    int jj = idx & 15;
    int b = idx >> 4;
    float gi = gbuf[b * 68 + jj];
    float gf = gbuf[b * 68 + 16 + jj];
    float gg = gbuf[b * 68 + 32 + jj];
    float go = gbuf[b * 68 + 48 + jj];
    int j = blk16 * 16 + jj;
    float cold = c[b * HID + j];
    float cn = sigm(gf) * cold + sigm(gi) * tanhf(gg);
    float hn = sigm(go) * tanhf(cn);
    c[b * HID + j] = cn;
    hout[b * HID + j] = f2b(hn);
    if (step >= 0) {
      size_t e = ((size_t)b * TG + step) * HID + j;
      stf(dout, OFF_H + e, hn, f32f);
      stf(dout, OFF_C + e, cn, f32f);
    }
  }
}

__global__ __launch_bounds__(256) void dec_step_k(
    const unsigned short* __restrict__ xdec,
    const unsigned short* __restrict__ hin, unsigned short* __restrict__ hout,
    float* __restrict__ cdec,
    const unsigned short* __restrict__ pkX, const unsigned short* __restrict__ pkH,
    const void* __restrict__ bias, void* dout, int step, const int* dtf) {
  cell_block<false>(xdec, hin, pkX, pkH, bias, cdec, hout, dout, step,
                    blockIdx.x, dtf[0]);
}

// attention[b][t][h] = concat(outF,outB)[t,b,:] @ attn_wm
__global__ __launch_bounds__(256) void attn_mm_k(
    const unsigned short* __restrict__ outF, const unsigned short* __restrict__ outB,
    const unsigned short* __restrict__ pkwm, unsigned short* __restrict__ att) {
  __shared__ char ldsA[4 * 1040];
  int bid = blockIdx.x;
  int bn = bid & 7, bm = bid >> 3;
  int tid = threadIdx.x, lane = tid & 63, wv = tid >> 6;
  int r0 = bm * 64;
  f32x4 acc[2][2] = {};
  int srow = tid >> 2, skb = tid & 3;
  int mt0 = (wv & 1) * 2, nt0 = (wv >> 1) * 2;
  for (int kk = 0; kk < 32; ++kk) {
    int kg = kk * 32 + skb * 8;
    const unsigned short* src = (kg < HID)
        ? (outF + (size_t)(r0 + srow) * HID + kg)
        : (outB + (size_t)(r0 + srow) * HID + (kg - HID));
    uint4 v = *(const uint4*)src;
    __syncthreads();
    *(uint4*)(ldsA + skb * 1040 + srow * 16) = v;
    __syncthreads();
    bf16x8 a[2], bb[2];
#pragma unroll
    for (int mi = 0; mi < 2; ++mi) {
      int rl = (mt0 + mi) * 16 + (lane & 15);
      a[mi] = *(const bf16x8*)(ldsA + (lane >> 4) * 1040 + rl * 16);
    }
#pragma unroll
    for (int nj = 0; nj < 2; ++nj) {
      int ntg = bn * 4 + nt0 + nj;
      bb[nj] = *(const bf16x8*)(pkwm + ((size_t)(ntg * 32 + kk) * 64 + lane) * 8);
    }
#pragma unroll
    for (int mi = 0; mi < 2; ++mi)
#pragma unroll
      for (int nj = 0; nj < 2; ++nj)
        acc[mi][nj] = __builtin_amdgcn_mfma_f32_16x16x32_bf16(a[mi], bb[nj], acc[mi][nj], 0, 0, 0);
  }
#pragma unroll
  for (int mi = 0; mi < 2; ++mi)
#pragma unroll
    for (int nj = 0; nj < 2; ++nj)
#pragma unroll
      for (int r = 0; r < 4; ++r) {
        int row = r0 + (mt0 + mi) * 16 + (lane >> 4) * 4 + r;
        int t = row >> 5, b = row & 31;
        int h = bn * 64 + (nt0 + nj) * 16 + (lane & 15);
        att[((size_t)b * TS + t) * HID + h] = f2b(acc[mi][nj][r]);
      }
}

__global__ void init_states_k(const void* __restrict__ ih, const void* __restrict__ ic,
                              unsigned short* hIF, unsigned short* hIB,
                              float* cF, float* cB, int* bar, const int* dtf) {
  int f32f = dtf[0];
  int g = blockIdx.x * 256 + threadIdx.x;   // 64 blocks
  if (g < 128) bar[g] = 0;                  // zero barrier counters each call
  int b = g >> 9, j = g & 511;
  hIF[b * HID + j] = f2b(ldf(ih, j, f32f));
  hIB[b * HID + j] = f2b(ldf(ih, HID + j, f32f));
  cF[b * HID + j] = ldf(ic, j, f32f);
  cB[b * HID + j] = ldf(ic, HID + j, f32f);
}

__global__ void seqmean_k(const unsigned short* __restrict__ att,
                          const int* __restrict__ lens, float* __restrict__ sm) {
  int b = blockIdx.x, tid = threadIdx.x;
  int len = lens[b];
  float a0 = 0.f, a1 = 0.f;
  for (int t = 0; t < len; ++t) {
    const unsigned short* row = att + ((size_t)b * TS + t) * HID;
    a0 += b2f(row[tid]);
    a1 += b2f(row[tid + 256]);
  }
  float fl = (float)len;
  sm[b * HID + tid] = a0 / fl;
  sm[b * HID + tid + 256] = a1 / fl;
}

__global__ void mv_bb_k(const unsigned short* __restrict__ A1,
                        const unsigned short* __restrict__ A2,
                        const void* __restrict__ W, unsigned short* __restrict__ o,
                        const int* dtf) {
  int f32f = dtf[0];
  int g = blockIdx.x * 256 + threadIdx.x;
  int b = g >> 9, n = g & 511;
  float acc = 0.f;
  for (int k = 0; k < HID; ++k) acc += b2f(A1[b * HID + k]) * ldf(W, (size_t)k * HID + n, f32f);
  for (int k = 0; k < HID; ++k) acc += b2f(A2[b * HID + k]) * ldf(W, (size_t)(HID + k) * HID + n, f32f);
  o[b * HID + n] = f2b(acc);
}

__global__ void mv_ff_k(const float* __restrict__ A1, const float* __restrict__ A2,
                        const void* __restrict__ W, float* __restrict__ o, const int* dtf) {
  int f32f = dtf[0];
  int g = blockIdx.x * 256 + threadIdx.x;
  int b = g >> 9, n = g & 511;
  float acc = 0.f;
  for (int k = 0; k < HID; ++k) acc += A1[b * HID + k] * ldf(W, (size_t)k * HID + n, f32f);
  for (int k = 0; k < HID; ++k) acc += A2[b * HID + k] * ldf(W, (size_t)(HID + k) * HID + n, f32f);
  o[b * HID + n] = acc;
}

__global__ void query_k(const unsigned short* __restrict__ h,
                        const void* __restrict__ W, float* __restrict__ q, const int* dtf) {
  int f32f = dtf[0];
  int g = blockIdx.x * 256 + threadIdx.x;
  int b = g >> 9, n = g & 511;
  float acc = 0.f;
  for (int k = 0; k < HID; ++k) acc += b2f(h[b * HID + k]) * ldf(W, (size_t)k * HID + n, f32f);
  q[b * HID + n] = acc;
}

__global__ __launch_bounds__(256) void score_k(const float* __restrict__ query,
                                               const unsigned short* __restrict__ att,
                                               float* __restrict__ score) {
  int bid = blockIdx.x;
  int b = bid >> 3, slice = bid & 7;
  int tid = threadIdx.x, lane = tid & 63, wv = tid >> 6;
  float q[8];
#pragma unroll
  for (int j = 0; j < 8; ++j) q[j] = query[b * HID + lane * 8 + j];
  for (int it = 0; it < 32; ++it) {
    int t = slice * 128 + wv * 32 + it;
    uint4 v = *(const uint4*)(att + ((size_t)b * TS + t) * HID + lane * 8);
    const unsigned short* pv = (const unsigned short*)&v;
    float s = 0.f;
#pragma unroll
    for (int j = 0; j < 8; ++j) s += q[j] * b2f(pv[j]);
    for (int off = 32; off; off >>= 1) s += __shfl_xor(s, off, 64);
    if (lane == 0) score[(size_t)b * TS + t] = s;
  }
}

__global__ void softmax_k(const float* __restrict__ score, const int* __restrict__ lens,
                          float* __restrict__ probs) {
  __shared__ float red[256];
  int b = blockIdx.x, tid = threadIdx.x;
  int len = lens[b];
  float s[4], mx = -1e30f;
#pragma unroll
  for (int i = 0; i < 4; ++i) {
    int t = tid + i * 256;
    float v = (t < len) ? score[(size_t)b * TS + t] : -1e30f;
    s[i] = v;
    mx = fmaxf(mx, v);
  }
  red[tid] = mx; __syncthreads();
  for (int st = 128; st; st >>= 1) { if (tid < st) red[tid] = fmaxf(red[tid], red[tid + st]); __syncthreads(); }
  mx = red[0]; __syncthreads();
  float e[4], sum = 0.f;
#pragma unroll
  for (int i = 0; i < 4; ++i) { e[i] = (s[i] > -1e29f) ? expf(s[i] - mx) : 0.f; sum += e[i]; }
  red[tid] = sum; __syncthreads();
  for (int st = 128; st; st >>= 1) { if (tid < st) red[tid] += red[tid + st]; __syncthreads(); }
  sum = red[0];
#pragma unroll
  for (int i = 0; i < 4; ++i) probs[(size_t)b * TS + tid + i * 256] = e[i] / sum;
}

__global__ void context_k(const float* __restrict__ probs,
                          const unsigned short* __restrict__ att, float* __restrict__ ctx) {
  int g = blockIdx.x * 256 + threadIdx.x;
  int b = g >> 9, h = g & 511;
  float acc = 0.f;
  for (int t = 0; t < TS; ++t)
    acc += probs[(size_t)b * TS + t] * b2f(att[((size_t)b * TS + t) * HID + h]);
  ctx[b * HID + h] = acc;
}

__global__ void proj1_k(const unsigned short* __restrict__ A1, const float* __restrict__ A2,
                        const void* __restrict__ W1p, const void* __restrict__ b1p,
                        unsigned short* __restrict__ z, const int* dtf) {
  int f32f = dtf[0];
  int g = blockIdx.x * 256 + threadIdx.x;
  int b = g >> 9, n = g & 511;
  float acc = ldf(b1p, n, f32f);
  for (int k = 0; k < HID; ++k) acc += b2f(A1[b * HID + k]) * ldf(W1p, (size_t)k * HID + n, f32f);
  for (int k = 0; k < HID; ++k) acc += A2[b * HID + k] * ldf(W1p, (size_t)(HID + k) * HID + n, f32f);
  z[b * HID + n] = f2b(tanhf(acc));
}

__global__ void proj2_k(const unsigned short* __restrict__ z,
                        const void* __restrict__ W2, const void* __restrict__ emb,
                        int inext, unsigned short* __restrict__ xdec,
                        void* dout, int step, const int* dtf) {
  int f32f = dtf[0];
  int g = blockIdx.x * 256 + threadIdx.x;
  int b = g >> 8, n = g & 255;
  float acc = 0.f;
  for (int k = 0; k < HID; ++k) acc += b2f(z[b * HID + k]) * ldf(W2, (size_t)k * EDIM + n, f32f);
  xdec[b * HID + EDIM + n] = f2b(acc);
  xdec[b * HID + n] = f2b(ldf(emb, (size_t)(SPECIAL + inext) * EDIM + n, f32f));
  if (step >= 0) stf(dout, ((size_t)b * TG + step) * EDIM + n, acc, f32f);
}

extern "C" void kernel_launch(void* const* d_in, const int* in_sizes, int n_in,
                              void* d_out, int out_size, void* d_ws, size_t ws_size,
                              hipStream_t stream) {
  (void)in_sizes; (void)n_in;
  const void* article = d_in[0];
  const int* art_lens = (const int*)d_in[1];
  const void* emb  = d_in[3];
  const void* eWxf = d_in[4]; const void* eWhf = d_in[5]; const void* ebf = d_in[6];
  const void* eWxb = d_in[7]; const void* eWhb = d_in[8]; const void* ebb = d_in[9];
  const void* initH = d_in[10]; const void* initC = d_in[11];
  const void* dhW = d_in[12]; const void* dcW = d_in[13];
  const void* wm = d_in[14]; const void* wq = d_in[15];
  const void* W1 = d_in[16]; const void* b1 = d_in[17]; const void* W2 = d_in[18];
  const void* dWx = d_in[19]; const void* dWh = d_in[20]; const void* db = d_in[21];

  char* ws = (char*)d_ws;
  size_t off = 0;
  auto take = [&](size_t bytes) -> char* {
    char* p = ws + off;
    off = (off + bytes + 255) & ~(size_t)255;
    return p;
  };
  int* dtf = (int*)take(4);
  int* bar = (int*)take(128 * 4);
  unsigned short* pk_exf = (unsigned short*)take((size_t)GD * HID * 2);
  unsigned short* pk_ehf = (unsigned short*)take((size_t)GD * HID * 2);
  unsigned short* pk_exb = (unsigned short*)take((size_t)GD * HID * 2);
  unsigned short* pk_ehb = (unsigned short*)take((size_t)GD * HID * 2);
  unsigned short* pk_dx  = (unsigned short*)take((size_t)GD * HID * 2);
  unsigned short* pk_dh  = (unsigned short*)take((size_t)GD * HID * 2);
  unsigned short* pk_wm  = (unsigned short*)take((size_t)1024 * HID * 2);
  unsigned short* outF = (unsigned short*)take((size_t)TS * BATCH * HID * 2);
  unsigned short* outB = (unsigned short*)take((size_t)TS * BATCH * HID * 2);
  unsigned short* att  = (unsigned short*)take((size_t)BATCH * TS * HID * 2);
  unsigned short* hIF  = (unsigned short*)take((size_t)BATCH * HID * 2);
  unsigned short* hIB  = (unsigned short*)take((size_t)BATCH * HID * 2);
  float* cF = (float*)take((size_t)BATCH * HID * 4);
  float* cB = (float*)take((size_t)BATCH * HID * 4);
  unsigned short* hd0 = (unsigned short*)take((size_t)BATCH * HID * 2);
  unsigned short* hd1 = (unsigned short*)take((size_t)BATCH * HID * 2);
  float* cdec = (float*)take((size_t)BATCH * HID * 4);
  unsigned short* xdec = (unsigned short*)take((size_t)BATCH * HID * 2);
  unsigned short* zbuf = (unsigned short*)take((size_t)BATCH * HID * 2);
  float* query = (float*)take((size_t)BATCH * HID * 4);
  float* scoreb = (float*)take((size_t)BATCH * TS * 4);
  float* probs = (float*)take((size_t)BATCH * TS * 4);
  float* ctx = (float*)take((size_t)BATCH * HID * 4);
  float* sm = (float*)take((size_t)BATCH * HID * 4);

  if (off > ws_size) {
    fill_sig_k<<<(out_size + 255) / 256, 256, 0, stream>>>((unsigned short*)d_out, out_size);
    return;
  }

  detect_k<<<1, 256, 0, stream>>>(article, dtf);
  pack_gate_k<<<512, 256, 0, stream>>>(eWxf, pk_exf, dtf);
  pack_gate_k<<<512, 256, 0, stream>>>(eWhf, pk_ehf, dtf);
  pack_gate_k<<<512, 256, 0, stream>>>(eWxb, pk_exb, dtf);
  pack_gate_k<<<512, 256, 0, stream>>>(eWhb, pk_ehb, dtf);
  pack_gate_k<<<512, 256, 0, stream>>>(dWx, pk_dx, dtf);
  pack_gate_k<<<512, 256, 0, stream>>>(dWh, pk_dh, dtf);
  pack_wm_k<<<256, 256, 0, stream>>>(wm, pk_wm, dtf);
  init_states_k<<<64, 256, 0, stream>>>(initH, initC, hIF, hIB, cF, cB, bar, dtf);

  // ---- encoder: ONE persistent dispatch (was 1024) ----
  enc_all_k<<<64, 256, 0, stream>>>(article, outF, outB, hIF, hIB, cF, cB,
                                    pk_exf, pk_ehf, pk_exb, pk_ehb, ebf, ebb,
                                    bar, dtf);

  attn_mm_k<<<4096, 256, 0, stream>>>(outF, outB, pk_wm, att);
  seqmean_k<<<32, 256, 0, stream>>>(att, art_lens, sm);
  mv_bb_k<<<64, 256, 0, stream>>>(outF + (size_t)(TS - 1) * BATCH * HID, outB, dhW, hd0, dtf);
  mv_ff_k<<<64, 256, 0, stream>>>(cF, cB, dcW, cdec, dtf);
  proj1_k<<<64, 256, 0, stream>>>(hd0, sm, W1, b1, zbuf, dtf);
  proj2_k<<<32, 256, 0, stream>>>(zbuf, W2, emb, 0, xdec, nullptr, -1, dtf);

  unsigned short* hcur = hd0;
  unsigned short* hnxt = hd1;
  for (int i = 0; i < TG; ++i) {
    dec_step_k<<<32, 256, 0, stream>>>(xdec, hcur, hnxt, cdec, pk_dx, pk_dh, db,
                                       d_out, i, dtf);
    query_k<<<64, 256, 0, stream>>>(hnxt, wq, query, dtf);
    score_k<<<256, 256, 0, stream>>>(query, att, scoreb);
    softmax_k<<<32, 256, 0, stream>>>(scoreb, art_lens, probs);
    context_k<<<64, 256, 0, stream>>>(probs, att, ctx);
    proj1_k<<<64, 256, 0, stream>>>(hnxt, ctx, W1, b1, zbuf, dtf);
    proj2_k<<<32, 256, 0, stream>>>(zbuf, W2, emb, i + 1, xdec, d_out, i, dtf);
    unsigned short* tmp = hcur; hcur = hnxt; hnxt = tmp;
  }
}

// Round 5
// 23344.749 us; speedup vs baseline: 1.4358x; 1.4358x over previous
//
#include <hip/hip_runtime.h>

// Seq2Seq summarizer forward. External tensors f32 (runtime-probed; bf16 also
// handled); internal compute bf16 MFMA + f32 state. ~110 MB ws.
// R5: persistent encoder keeps register-resident weights, but the R4
// fence+single-counter barrier (L2 writeback/invalidate per step, serialized
// atomics) is replaced by TARGETED coherence: h exchanged via relaxed
// agent-scope atomic dwords, release = syncthreads vmcnt-drain, distributed
// per-block epoch flags polled lane-parallel. No __threadfence in the loop.

#define DI __device__ __forceinline__

constexpr int BATCH = 32;
constexpr int TS = 1024;
constexpr int TG = 64;
constexpr int HID = 512;
constexpr int GD = 2048;     // 4*HID
constexpr int EDIM = 256;
constexpr int SPECIAL = 4;
constexpr size_t OFF_H = (size_t)BATCH * TG * EDIM;         // h_all elem offset in d_out
constexpr size_t OFF_C = OFF_H + (size_t)BATCH * TG * HID;  // c_all elem offset
constexpr int FLAG_STRIDE = 16;                             // dwords (64B) per flag

typedef __attribute__((ext_vector_type(8))) short bf16x8;
typedef __attribute__((ext_vector_type(4))) float f32x4;

DI float b2f(unsigned short u) {
  union { unsigned int i; float f; } v; v.i = ((unsigned int)u) << 16; return v.f;
}
DI unsigned short f2b(float f) {
  union { float f; unsigned int i; } v; v.f = f;
  unsigned int r = v.i + 0x7fffu + ((v.i >> 16) & 1u);
  return (unsigned short)(r >> 16);
}
DI float sigm(float x) { return 1.0f / (1.0f + expf(-x)); }
DI float ldf(const void* p, size_t i, int f32f) {
  return f32f ? ((const float*)p)[i] : b2f(((const unsigned short*)p)[i]);
}
DI void stf(void* p, size_t i, float v, int f32f) {
  if (f32f) ((float*)p)[i] = v; else ((unsigned short*)p)[i] = f2b(v);
}

// dtype probe: f32 N(0,1) words are "sane"; bf16 pairs read as f32 are wild.
__global__ void detect_k(const void* art, int* flag) {
  int tid = threadIdx.x;
  float x = ((const float*)art)[tid + 1024];
  float a = fabsf(x);
  int sane = (x == 0.0f) || (a > 1e-8f && a < 1e4f);
  unsigned long long m = __ballot(sane);
  __shared__ int cnt[4];
  if ((tid & 63) == 0) cnt[tid >> 6] = __popcll(m);
  __syncthreads();
  if (tid == 0) flag[0] = (cnt[0] + cnt[1] + cnt[2] + cnt[3] > 128) ? 1 : 0;
}

__global__ void fill_sig_k(unsigned short* o, int n) {
  int g = blockIdx.x * 256 + threadIdx.x;
  if (g < n) o[g] = 0x42F6;  // ws-too-small signature (~123)
}

// Pack W[GD][HID] -> MFMA B-frags, gate-interleaved per 16-hidden-unit block.
__global__ void pack_gate_k(const void* __restrict__ W,
                            unsigned short* __restrict__ pk, const int* dtf) {
  int f32f = dtf[0];
  int g = blockIdx.x * 256 + threadIdx.x;
  if (g >= (GD * HID) / 8) return;
  int lane = g & 63;
  int kk = (g >> 6) & 15;
  int tile = g >> 10;
  int p = tile * 16 + (lane & 15);
  int nloc = p & 63, blk = p >> 6;
  int orow = (nloc >> 4) * HID + blk * 16 + (nloc & 15);
  int k = kk * 32 + (lane >> 4) * 8;
  unsigned short tmp[8];
#pragma unroll
  for (int j = 0; j < 8; ++j) tmp[j] = f2b(ldf(W, (size_t)orow * HID + k + j, f32f));
  *(uint4*)(pk + (size_t)g * 8) = *(uint4*)tmp;
}

__global__ void pack_wm_k(const void* __restrict__ wm,
                          unsigned short* __restrict__ pk, const int* dtf) {
  int f32f = dtf[0];
  int g = blockIdx.x * 256 + threadIdx.x;
  if (g >= 32 * 32 * 64) return;
  int lane = g & 63;
  int kk = (g >> 6) & 31;
  int nt = g >> 11;
  int col = nt * 16 + (lane & 15);
  int kb = kk * 32 + (lane >> 4) * 8;
  unsigned short tmp[8];
#pragma unroll
  for (int j = 0; j < 8; ++j) tmp[j] = f2b(ldf(wm, (size_t)(kb + j) * HID + col, f32f));
  *(uint4*)(pk + (size_t)g * 8) = *(uint4*)tmp;
}

// ---------------------------------------------------------------------------
// Persistent bidirectional encoder. 64 blocks (32 fwd + 32 bwd), co-resident
// (<=256 CUs). Weights in VGPRs, c in regs. Cross-block h handoff:
//   store h as relaxed agent-scope dwords -> __syncthreads (vmcnt drain =
//   release) -> relaxed agent flag store (epoch t+1) -> lane-parallel relaxed
//   agent polls of all 32 peer flags -> agent-scope h loads next step.
// No cache-wide fences anywhere in the loop.
// ---------------------------------------------------------------------------
__global__ __launch_bounds__(256, 1) void enc_all_k(
    const void* __restrict__ article,
    unsigned short* __restrict__ outF, unsigned short* __restrict__ outB,
    const unsigned short* __restrict__ hIF, const unsigned short* __restrict__ hIB,
    float* __restrict__ cF, float* __restrict__ cB,
    const unsigned short* __restrict__ pkXF, const unsigned short* __restrict__ pkHF,
    const unsigned short* __restrict__ pkXB, const unsigned short* __restrict__ pkHB,
    const void* __restrict__ bF, const void* __restrict__ bB,
    int* __restrict__ bar, const int* dtf) {
  const int f32f = dtf[0];
  const int blk = blockIdx.x;
  const int dir = blk >> 5;
  const int blk16 = blk & 31;
  const int tid = threadIdx.x;
  const int lane = tid & 63;
  const int wv = tid >> 6;
  const int tile = blk16 * 4 + wv;

  __shared__ unsigned short lstage[BATCH * HID];  // 32 KB
  __shared__ float gbuf[BATCH * 68];              // 8.5 KB

  const unsigned short* pkX = dir ? pkXB : pkXF;
  const unsigned short* pkH = dir ? pkHB : pkHF;
  const void* bias = dir ? bB : bF;
  unsigned short* out = dir ? outB : outF;
  const unsigned short* hI = dir ? hIB : hIF;
  float* cg = dir ? cB : cF;
  int* flp = bar + dir * 32 * FLAG_STRIDE;

  // ---- weights -> VGPRs (this wave's n-tile, all K) ----
  bf16x8 wx[16], wh[16];
  {
    const unsigned short* px = pkX + ((size_t)tile * 16 * 64 + lane) * 8;
    const unsigned short* ph = pkH + ((size_t)tile * 16 * 64 + lane) * 8;
#pragma unroll
    for (int kk = 0; kk < 16; ++kk) {
      wx[kk] = *(const bf16x8*)(px + (size_t)kk * 64 * 8);
      wh[kk] = *(const bf16x8*)(ph + (size_t)kk * 64 * 8);
    }
  }
  // ---- c state -> registers. Thread owns (b = tid>>3, jj = (tid&7)*2, +1)
  // so its two h outputs pack into one dword for the agent store.
  const int gb = tid >> 3;
  const int gj = (tid & 7) * 2;
  float c0 = cg[gb * HID + blk16 * 16 + gj];
  float c1 = cg[gb * HID + blk16 * 16 + gj + 1];

  const int r0 = lane & 15;
  const int r1 = 16 + r0;
  const int kbb = (lane >> 4) * 8;
  const int nloc = wv * 16 + (lane & 15);
  const int orow = (nloc >> 4) * HID + blk16 * 16 + (nloc & 15);
  const float bv = ldf(bias, orow, f32f);

  for (int t = 0; t < TS; ++t) {
    const int tsrc = dir ? (TS - 1 - t) : t;
    // ---- stage x(tsrc) into LDS (plain cached loads; f32->bf16) ----
#pragma unroll
    for (int it = 0; it < 8; ++it) {
      int ci = it * 256 + tid;
      int row = ci >> 6;
      int k8 = (ci & 63) << 3;
      unsigned off = (unsigned)(row * 1024 + ((k8 * 2) ^ ((row & 7) << 4)));
      if (f32f) {
        const float* s = (const float*)article + (size_t)tsrc * BATCH * HID +
                         (size_t)row * HID + k8;
        float4 u0 = *(const float4*)s;
        float4 u1 = *(const float4*)(s + 4);
        unsigned short tmp[8] = {f2b(u0.x), f2b(u0.y), f2b(u0.z), f2b(u0.w),
                                 f2b(u1.x), f2b(u1.y), f2b(u1.z), f2b(u1.w)};
        *(uint4*)((char*)lstage + off) = *(uint4*)tmp;
      } else {
        const unsigned short* s = (const unsigned short*)article +
                                  (size_t)tsrc * BATCH * HID + (size_t)row * HID + k8;
        *(uint4*)((char*)lstage + off) = *(const uint4*)s;
      }
    }
    __syncthreads();
    // ---- issue h(prev) agent-scope loads early (hidden under x-MFMA) ----
    unsigned int* hu = (t == 0)
        ? (unsigned int*)hI
        : (unsigned int*)(out + (size_t)(tsrc + (dir ? 1 : -1)) * BATCH * HID);
    unsigned int hreg[32];
#pragma unroll
    for (int it = 0; it < 32; ++it)
      hreg[it] = __hip_atomic_load(hu + it * 256 + tid, __ATOMIC_RELAXED,
                                   __HIP_MEMORY_SCOPE_AGENT);
    // ---- x pass ----
    f32x4 acc0 = {0.f, 0.f, 0.f, 0.f};
    f32x4 acc1 = {0.f, 0.f, 0.f, 0.f};
#pragma unroll
    for (int kk = 0; kk < 16; ++kk) {
      unsigned o0 = (unsigned)(r0 * 1024 + (((kk * 32 + kbb) * 2) ^ ((r0 & 7) << 4)));
      unsigned o1 = (unsigned)(r1 * 1024 + (((kk * 32 + kbb) * 2) ^ ((r0 & 7) << 4)));
      bf16x8 a0 = *(const bf16x8*)((const char*)lstage + o0);
      bf16x8 a1 = *(const bf16x8*)((const char*)lstage + o1);
      acc0 = __builtin_amdgcn_mfma_f32_16x16x32_bf16(a0, wx[kk], acc0, 0, 0, 0);
      acc1 = __builtin_amdgcn_mfma_f32_16x16x32_bf16(a1, wx[kk], acc1, 0, 0, 0);
    }
    __syncthreads();                  // x reads done before overwrite
    // ---- write h into LDS (dword-granular, same 16B XOR swizzle) ----
#pragma unroll
    for (int it = 0; it < 32; ++it) {
      int dw = it * 256 + tid;
      int row = dw >> 8;
      unsigned lb = (unsigned)(row * 1024 +
                               (((dw & 252) << 2) ^ ((row & 7) << 4)) +
                               ((dw & 3) << 2));
      *(unsigned int*)((char*)lstage + lb) = hreg[it];
    }
    __syncthreads();
    // ---- h pass ----
#pragma unroll
    for (int kk = 0; kk < 16; ++kk) {
      unsigned o0 = (unsigned)(r0 * 1024 + (((kk * 32 + kbb) * 2) ^ ((r0 & 7) << 4)));
      unsigned o1 = (unsigned)(r1 * 1024 + (((kk * 32 + kbb) * 2) ^ ((r0 & 7) << 4)));
      bf16x8 a0 = *(const bf16x8*)((const char*)lstage + o0);
      bf16x8 a1 = *(const bf16x8*)((const char*)lstage + o1);
      acc0 = __builtin_amdgcn_mfma_f32_16x16x32_bf16(a0, wh[kk], acc0, 0, 0, 0);
      acc1 = __builtin_amdgcn_mfma_f32_16x16x32_bf16(a1, wh[kk], acc1, 0, 0, 0);
    }
#pragma unroll
    for (int r = 0; r < 4; ++r) {
      int brow = (lane >> 4) * 4 + r;
      gbuf[brow * 68 + nloc] = acc0[r] + bv;
      gbuf[(16 + brow) * 68 + nloc] = acc1[r] + bv;
    }
    __syncthreads();
    // ---- gates -> c,h; store packed h dword agent-scope ----
    {
      float gi0 = gbuf[gb * 68 + gj],      gf0 = gbuf[gb * 68 + 16 + gj];
      float gg0 = gbuf[gb * 68 + 32 + gj], go0 = gbuf[gb * 68 + 48 + gj];
      float gi1 = gbuf[gb * 68 + gj + 1],      gf1 = gbuf[gb * 68 + 16 + gj + 1];
      float gg1 = gbuf[gb * 68 + 32 + gj + 1], go1 = gbuf[gb * 68 + 48 + gj + 1];
      float cn0 = sigm(gf0) * c0 + sigm(gi0) * tanhf(gg0); c0 = cn0;
      float cn1 = sigm(gf1) * c1 + sigm(gi1) * tanhf(gg1); c1 = cn1;
      float hn0 = sigm(go0) * tanhf(cn0);
      float hn1 = sigm(go1) * tanhf(cn1);
      unsigned int hv = (unsigned int)f2b(hn0) | ((unsigned int)f2b(hn1) << 16);
      unsigned int* outu = (unsigned int*)out + (size_t)tsrc * (BATCH * HID / 2) +
                           gb * (HID / 2) + blk16 * 8 + (tid & 7);
      __hip_atomic_store(outu, hv, __ATOMIC_RELAXED, __HIP_MEMORY_SCOPE_AGENT);
    }
    // ---- epoch barrier: drain stores, set flag, poll 32 peer flags ----
    if (t + 1 < TS) {
      __syncthreads();   // hipcc emits s_waitcnt vmcnt(0) before s_barrier:
                         // every thread's h store is globally complete here.
      if (wv == 0) {
        const int target = t + 1;
        if (lane == 0)
          __hip_atomic_store(flp + blk16 * FLAG_STRIDE, target,
                             __ATOMIC_RELAXED, __HIP_MEMORY_SCOPE_AGENT);
        for (;;) {
          int v = (lane < 32)
              ? __hip_atomic_load(flp + lane * FLAG_STRIDE, __ATOMIC_RELAXED,
                                  __HIP_MEMORY_SCOPE_AGENT)
              : 0x7fffffff;
          if (__all(v >= target)) break;
          __builtin_amdgcn_s_sleep(2);
        }
      }
      __syncthreads();
    }
  }
  // ---- final c back to global (visible to next dispatch via kernel-end) ----
  cg[gb * HID + blk16 * 16 + gj] = c0;
  cg[gb * HID + blk16 * 16 + gj + 1] = c1;
}

// LSTM cell (decoder path), per-block hidden slice: unchanged.
template <bool EXTX>
DI void cell_block(const void* __restrict__ xg,
                   const unsigned short* __restrict__ hg,
                   const unsigned short* __restrict__ pkX,
                   const unsigned short* __restrict__ pkH,
                   const void* __restrict__ bias,
                   float* __restrict__ c,
                   unsigned short* __restrict__ hout,
                   void* dout, int step, int blk16, int f32f) {
  __shared__ unsigned short lstage[BATCH * HID];
  __shared__ float gbuf[BATCH * 68];
  const int tid = threadIdx.x;
  const int lane = tid & 63;
  const int wv = tid >> 6;
  const int tile = blk16 * 4 + wv;
  const int r0 = lane & 15;
  const int r1 = 16 + r0;
  const int kbb = (lane >> 4) * 8;
  f32x4 acc0 = {0.f, 0.f, 0.f, 0.f};
  f32x4 acc1 = {0.f, 0.f, 0.f, 0.f};

  for (int pass = 0; pass < 2; ++pass) {
    const unsigned short* pw = (pass ? pkH : pkX) + (size_t)tile * 16 * 64 * 8;
    if (pass) __syncthreads();
#pragma unroll
    for (int it = 0; it < 8; ++it) {
      int ci = it * 256 + tid;
      int row = ci >> 6;
      int k8 = (ci & 63) << 3;
      unsigned off = (unsigned)(row * 1024 + ((k8 * 2) ^ ((row & 7) << 4)));
      if (pass == 0 && EXTX && f32f) {
        const float* s = (const float*)xg + (size_t)row * HID + k8;
        float4 u0 = *(const float4*)s;
        float4 u1 = *(const float4*)(s + 4);
        unsigned short tmp[8] = {f2b(u0.x), f2b(u0.y), f2b(u0.z), f2b(u0.w),
                                 f2b(u1.x), f2b(u1.y), f2b(u1.z), f2b(u1.w)};
        *(uint4*)((char*)lstage + off) = *(uint4*)tmp;
      } else {
        const unsigned short* s =
            pass ? hg + (size_t)row * HID + k8
                 : (const unsigned short*)xg + (size_t)row * HID + k8;
        *(uint4*)((char*)lstage + off) = *(const uint4*)s;
      }
    }
    __syncthreads();
#pragma unroll
    for (int kk = 0; kk < 16; ++kk) {
      unsigned o0 = (unsigned)(r0 * 1024 + (((kk * 32 + kbb) * 2) ^ ((r0 & 7) << 4)));
      unsigned o1 = (unsigned)(r1 * 1024 + (((kk * 32 + kbb) * 2) ^ ((r0 & 7) << 4)));
      bf16x8 a0 = *(const bf16x8*)((const char*)lstage + o0);
      bf16x8 a1 = *(const bf16x8*)((const char*)lstage + o1);
      bf16x8 bb = *(const bf16x8*)(pw + (size_t)(kk * 64 + lane) * 8);
      acc0 = __builtin_amdgcn_mfma_f32_16x16x32_bf16(a0, bb, acc0, 0, 0, 0);
      acc1 = __builtin_amdgcn_mfma_f32_16x16x32_bf16(a1, bb, acc1, 0, 0, 0);
    }
  }
  const int nloc = wv * 16 + (lane & 15);
  const int orow = (nloc >> 4) * HID + blk16 * 16 + (nloc & 15);
  const float bv = ldf(bias, orow, f32f);
#pragma unroll
  for (int r = 0; r < 4; ++r) {
    int brow = (lane >> 4) * 4 + r;
    gbuf[brow * 68 + nloc] = acc0[r] + bv;
    gbuf[(16 + brow) * 68 + nloc] = acc1[r] + bv;
  }
  __syncthreads();
#pragma unroll
  for (int it = 0; it < 2; ++it) {
    int idx = it * 256 + tid;
    int jj = idx & 15;
    int b = idx >> 4;
    float gi = gbuf[b * 68 + jj];
    float gf = gbuf[b * 68 + 16 + jj];
    float gg = gbuf[b * 68 + 32 + jj];
    float go = gbuf[b * 68 + 48 + jj];
    int j = blk16 * 16 + jj;
    float cold = c[b * HID + j];
    float cn = sigm(gf) * cold + sigm(gi) * tanhf(gg);
    float hn = sigm(go) * tanhf(cn);
    c[b * HID + j] = cn;
    hout[b * HID + j] = f2b(hn);
    if (step >= 0) {
      size_t e = ((size_t)b * TG + step) * HID + j;
      stf(dout, OFF_H + e, hn, f32f);
      stf(dout, OFF_C + e, cn, f32f);
    }
  }
}

__global__ __launch_bounds__(256) void dec_step_k(
    const unsigned short* __restrict__ xdec,
    const unsigned short* __restrict__ hin, unsigned short* __restrict__ hout,
    float* __restrict__ cdec,
    const unsigned short* __restrict__ pkX, const unsigned short* __restrict__ pkH,
    const void* __restrict__ bias, void* dout, int step, const int* dtf) {
  cell_block<false>(xdec, hin, pkX, pkH, bias, cdec, hout, dout, step,
                    blockIdx.x, dtf[0]);
}

// attention[b][t][h] = concat(outF,outB)[t,b,:] @ attn_wm
__global__ __launch_bounds__(256) void attn_mm_k(
    const unsigned short* __restrict__ outF, const unsigned short* __restrict__ outB,
    const unsigned short* __restrict__ pkwm, unsigned short* __restrict__ att) {
  __shared__ char ldsA[4 * 1040];
  int bid = blockIdx.x;
  int bn = bid & 7, bm = bid >> 3;
  int tid = threadIdx.x, lane = tid & 63, wv = tid >> 6;
  int r0 = bm * 64;
  f32x4 acc[2][2] = {};
  int srow = tid >> 2, skb = tid & 3;
  int mt0 = (wv & 1) * 2, nt0 = (wv >> 1) * 2;
  for (int kk = 0; kk < 32; ++kk) {
    int kg = kk * 32 + skb * 8;
    const unsigned short* src = (kg < HID)
        ? (outF + (size_t)(r0 + srow) * HID + kg)
        : (outB + (size_t)(r0 + srow) * HID + (kg - HID));
    uint4 v = *(const uint4*)src;
    __syncthreads();
    *(uint4*)(ldsA + skb * 1040 + srow * 16) = v;
    __syncthreads();
    bf16x8 a[2], bb[2];
#pragma unroll
    for (int mi = 0; mi < 2; ++mi) {
      int rl = (mt0 + mi) * 16 + (lane & 15);
      a[mi] = *(const bf16x8*)(ldsA + (lane >> 4) * 1040 + rl * 16);
    }
#pragma unroll
    for (int nj = 0; nj < 2; ++nj) {
      int ntg = bn * 4 + nt0 + nj;
      bb[nj] = *(const bf16x8*)(pkwm + ((size_t)(ntg * 32 + kk) * 64 + lane) * 8);
    }
#pragma unroll
    for (int mi = 0; mi < 2; ++mi)
#pragma unroll
      for (int nj = 0; nj < 2; ++nj)
        acc[mi][nj] = __builtin_amdgcn_mfma_f32_16x16x32_bf16(a[mi], bb[nj], acc[mi][nj], 0, 0, 0);
  }
#pragma unroll
  for (int mi = 0; mi < 2; ++mi)
#pragma unroll
    for (int nj = 0; nj < 2; ++nj)
#pragma unroll
      for (int r = 0; r < 4; ++r) {
        int row = r0 + (mt0 + mi) * 16 + (lane >> 4) * 4 + r;
        int t = row >> 5, b = row & 31;
        int h = bn * 64 + (nt0 + nj) * 16 + (lane & 15);
        att[((size_t)b * TS + t) * HID + h] = f2b(acc[mi][nj][r]);
      }
}

__global__ void init_states_k(const void* __restrict__ ih, const void* __restrict__ ic,
                              unsigned short* hIF, unsigned short* hIB,
                              float* cF, float* cB, int* bar, const int* dtf) {
  int f32f = dtf[0];
  int g = blockIdx.x * 256 + threadIdx.x;   // 64 blocks
  if (g < 2 * 32 * FLAG_STRIDE)             // zero flags, agent-scope (coherent)
    __hip_atomic_store(bar + g, 0, __ATOMIC_RELAXED, __HIP_MEMORY_SCOPE_AGENT);
  int b = g >> 9, j = g & 511;
  hIF[b * HID + j] = f2b(ldf(ih, j, f32f));
  hIB[b * HID + j] = f2b(ldf(ih, HID + j, f32f));
  cF[b * HID + j] = ldf(ic, j, f32f);
  cB[b * HID + j] = ldf(ic, HID + j, f32f);
}

__global__ void seqmean_k(const unsigned short* __restrict__ att,
                          const int* __restrict__ lens, float* __restrict__ sm) {
  int b = blockIdx.x, tid = threadIdx.x;
  int len = lens[b];
  float a0 = 0.f, a1 = 0.f;
  for (int t = 0; t < len; ++t) {
    const unsigned short* row = att + ((size_t)b * TS + t) * HID;
    a0 += b2f(row[tid]);
    a1 += b2f(row[tid + 256]);
  }
  float fl = (float)len;
  sm[b * HID + tid] = a0 / fl;
  sm[b * HID + tid + 256] = a1 / fl;
}

__global__ void mv_bb_k(const unsigned short* __restrict__ A1,
                        const unsigned short* __restrict__ A2,
                        const void* __restrict__ W, unsigned short* __restrict__ o,
                        const int* dtf) {
  int f32f = dtf[0];
  int g = blockIdx.x * 256 + threadIdx.x;
  int b = g >> 9, n = g & 511;
  float acc = 0.f;
  for (int k = 0; k < HID; ++k) acc += b2f(A1[b * HID + k]) * ldf(W, (size_t)k * HID + n, f32f);
  for (int k = 0; k < HID; ++k) acc += b2f(A2[b * HID + k]) * ldf(W, (size_t)(HID + k) * HID + n, f32f);
  o[b * HID + n] = f2b(acc);
}

__global__ void mv_ff_k(const float* __restrict__ A1, const float* __restrict__ A2,
                        const void* __restrict__ W, float* __restrict__ o, const int* dtf) {
  int f32f = dtf[0];
  int g = blockIdx.x * 256 + threadIdx.x;
  int b = g >> 9, n = g & 511;
  float acc = 0.f;
  for (int k = 0; k < HID; ++k) acc += A1[b * HID + k] * ldf(W, (size_t)k * HID + n, f32f);
  for (int k = 0; k < HID; ++k) acc += A2[b * HID + k] * ldf(W, (size_t)(HID + k) * HID + n, f32f);
  o[b * HID + n] = acc;
}

__global__ void query_k(const unsigned short* __restrict__ h,
                        const void* __restrict__ W, float* __restrict__ q, const int* dtf) {
  int f32f = dtf[0];
  int g = blockIdx.x * 256 + threadIdx.x;
  int b = g >> 9, n = g & 511;
  float acc = 0.f;
  for (int k = 0; k < HID; ++k) acc += b2f(h[b * HID + k]) * ldf(W, (size_t)k * HID + n, f32f);
  q[b * HID + n] = acc;
}

__global__ __launch_bounds__(256) void score_k(const float* __restrict__ query,
                                               const unsigned short* __restrict__ att,
                                               float* __restrict__ score) {
  int bid = blockIdx.x;
  int b = bid >> 3, slice = bid & 7;
  int tid = threadIdx.x, lane = tid & 63, wv = tid >> 6;
  float q[8];
#pragma unroll
  for (int j = 0; j < 8; ++j) q[j] = query[b * HID + lane * 8 + j];
  for (int it = 0; it < 32; ++it) {
    int t = slice * 128 + wv * 32 + it;
    uint4 v = *(const uint4*)(att + ((size_t)b * TS + t) * HID + lane * 8);
    const unsigned short* pv = (const unsigned short*)&v;
    float s = 0.f;
#pragma unroll
    for (int j = 0; j < 8; ++j) s += q[j] * b2f(pv[j]);
    for (int off = 32; off; off >>= 1) s += __shfl_xor(s, off, 64);
    if (lane == 0) score[(size_t)b * TS + t] = s;
  }
}

__global__ void softmax_k(const float* __restrict__ score, const int* __restrict__ lens,
                          float* __restrict__ probs) {
  __shared__ float red[256];
  int b = blockIdx.x, tid = threadIdx.x;
  int len = lens[b];
  float s[4], mx = -1e30f;
#pragma unroll
  for (int i = 0; i < 4; ++i) {
    int t = tid + i * 256;
    float v = (t < len) ? score[(size_t)b * TS + t] : -1e30f;
    s[i] = v;
    mx = fmaxf(mx, v);
  }
  red[tid] = mx; __syncthreads();
  for (int st = 128; st; st >>= 1) { if (tid < st) red[tid] = fmaxf(red[tid], red[tid + st]); __syncthreads(); }
  mx = red[0]; __syncthreads();
  float e[4], sum = 0.f;
#pragma unroll
  for (int i = 0; i < 4; ++i) { e[i] = (s[i] > -1e29f) ? expf(s[i] - mx) : 0.f; sum += e[i]; }
  red[tid] = sum; __syncthreads();
  for (int st = 128; st; st >>= 1) { if (tid < st) red[tid] += red[tid + st]; __syncthreads(); }
  sum = red[0];
#pragma unroll
  for (int i = 0; i < 4; ++i) probs[(size_t)b * TS + tid + i * 256] = e[i] / sum;
}

__global__ void context_k(const float* __restrict__ probs,
                          const unsigned short* __restrict__ att, float* __restrict__ ctx) {
  int g = blockIdx.x * 256 + threadIdx.x;
  int b = g >> 9, h = g & 511;
  float acc = 0.f;
  for (int t = 0; t < TS; ++t)
    acc += probs[(size_t)b * TS + t] * b2f(att[((size_t)b * TS + t) * HID + h]);
  ctx[b * HID + h] = acc;
}

__global__ void proj1_k(const unsigned short* __restrict__ A1, const float* __restrict__ A2,
                        const void* __restrict__ W1p, const void* __restrict__ b1p,
                        unsigned short* __restrict__ z, const int* dtf) {
  int f32f = dtf[0];
  int g = blockIdx.x * 256 + threadIdx.x;
  int b = g >> 9, n = g & 511;
  float acc = ldf(b1p, n, f32f);
  for (int k = 0; k < HID; ++k) acc += b2f(A1[b * HID + k]) * ldf(W1p, (size_t)k * HID + n, f32f);
  for (int k = 0; k < HID; ++k) acc += A2[b * HID + k] * ldf(W1p, (size_t)(HID + k) * HID + n, f32f);
  z[b * HID + n] = f2b(tanhf(acc));
}

__global__ void proj2_k(const unsigned short* __restrict__ z,
                        const void* __restrict__ W2, const void* __restrict__ emb,
                        int inext, unsigned short* __restrict__ xdec,
                        void* dout, int step, const int* dtf) {
  int f32f = dtf[0];
  int g = blockIdx.x * 256 + threadIdx.x;
  int b = g >> 8, n = g & 255;
  float acc = 0.f;
  for (int k = 0; k < HID; ++k) acc += b2f(z[b * HID + k]) * ldf(W2, (size_t)k * EDIM + n, f32f);
  xdec[b * HID + EDIM + n] = f2b(acc);
  xdec[b * HID + n] = f2b(ldf(emb, (size_t)(SPECIAL + inext) * EDIM + n, f32f));
  if (step >= 0) stf(dout, ((size_t)b * TG + step) * EDIM + n, acc, f32f);
}

extern "C" void kernel_launch(void* const* d_in, const int* in_sizes, int n_in,
                              void* d_out, int out_size, void* d_ws, size_t ws_size,
                              hipStream_t stream) {
  (void)in_sizes; (void)n_in;
  const void* article = d_in[0];
  const int* art_lens = (const int*)d_in[1];
  const void* emb  = d_in[3];
  const void* eWxf = d_in[4]; const void* eWhf = d_in[5]; const void* ebf = d_in[6];
  const void* eWxb = d_in[7]; const void* eWhb = d_in[8]; const void* ebb = d_in[9];
  const void* initH = d_in[10]; const void* initC = d_in[11];
  const void* dhW = d_in[12]; const void* dcW = d_in[13];
  const void* wm = d_in[14]; const void* wq = d_in[15];
  const void* W1 = d_in[16]; const void* b1 = d_in[17]; const void* W2 = d_in[18];
  const void* dWx = d_in[19]; const void* dWh = d_in[20]; const void* db = d_in[21];

  char* ws = (char*)d_ws;
  size_t off = 0;
  auto take = [&](size_t bytes) -> char* {
    char* p = ws + off;
    off = (off + bytes + 255) & ~(size_t)255;
    return p;
  };
  int* dtf = (int*)take(4);
  int* bar = (int*)take(2 * 32 * FLAG_STRIDE * 4);
  unsigned short* pk_exf = (unsigned short*)take((size_t)GD * HID * 2);
  unsigned short* pk_ehf = (unsigned short*)take((size_t)GD * HID * 2);
  unsigned short* pk_exb = (unsigned short*)take((size_t)GD * HID * 2);
  unsigned short* pk_ehb = (unsigned short*)take((size_t)GD * HID * 2);
  unsigned short* pk_dx  = (unsigned short*)take((size_t)GD * HID * 2);
  unsigned short* pk_dh  = (unsigned short*)take((size_t)GD * HID * 2);
  unsigned short* pk_wm  = (unsigned short*)take((size_t)1024 * HID * 2);
  unsigned short* outF = (unsigned short*)take((size_t)TS * BATCH * HID * 2);
  unsigned short* outB = (unsigned short*)take((size_t)TS * BATCH * HID * 2);
  unsigned short* att  = (unsigned short*)take((size_t)BATCH * TS * HID * 2);
  unsigned short* hIF  = (unsigned short*)take((size_t)BATCH * HID * 2);
  unsigned short* hIB  = (unsigned short*)take((size_t)BATCH * HID * 2);
  float* cF = (float*)take((size_t)BATCH * HID * 4);
  float* cB = (float*)take((size_t)BATCH * HID * 4);
  unsigned short* hd0 = (unsigned short*)take((size_t)BATCH * HID * 2);
  unsigned short* hd1 = (unsigned short*)take((size_t)BATCH * HID * 2);
  float* cdec = (float*)take((size_t)BATCH * HID * 4);
  unsigned short* xdec = (unsigned short*)take((size_t)BATCH * HID * 2);
  unsigned short* zbuf = (unsigned short*)take((size_t)BATCH * HID * 2);
  float* query = (float*)take((size_t)BATCH * HID * 4);
  float* scoreb = (float*)take((size_t)BATCH * TS * 4);
  float* probs = (float*)take((size_t)BATCH * TS * 4);
  float* ctx = (float*)take((size_t)BATCH * HID * 4);
  float* sm = (float*)take((size_t)BATCH * HID * 4);

  if (off > ws_size) {
    fill_sig_k<<<(out_size + 255) / 256, 256, 0, stream>>>((unsigned short*)d_out, out_size);
    return;
  }

  detect_k<<<1, 256, 0, stream>>>(article, dtf);
  pack_gate_k<<<512, 256, 0, stream>>>(eWxf, pk_exf, dtf);
  pack_gate_k<<<512, 256, 0, stream>>>(eWhf, pk_ehf, dtf);
  pack_gate_k<<<512, 256, 0, stream>>>(eWxb, pk_exb, dtf);
  pack_gate_k<<<512, 256, 0, stream>>>(eWhb, pk_ehb, dtf);
  pack_gate_k<<<512, 256, 0, stream>>>(dWx, pk_dx, dtf);
  pack_gate_k<<<512, 256, 0, stream>>>(dWh, pk_dh, dtf);
  pack_wm_k<<<256, 256, 0, stream>>>(wm, pk_wm, dtf);
  init_states_k<<<64, 256, 0, stream>>>(initH, initC, hIF, hIB, cF, cB, bar, dtf);

  // ---- encoder: ONE persistent dispatch, fence-free epoch barrier ----
  enc_all_k<<<64, 256, 0, stream>>>(article, outF, outB, hIF, hIB, cF, cB,
                                    pk_exf, pk_ehf, pk_exb, pk_ehb, ebf, ebb,
                                    bar, dtf);

  attn_mm_k<<<4096, 256, 0, stream>>>(outF, outB, pk_wm, att);
  seqmean_k<<<32, 256, 0, stream>>>(att, art_lens, sm);
  mv_bb_k<<<64, 256, 0, stream>>>(outF + (size_t)(TS - 1) * BATCH * HID, outB, dhW, hd0, dtf);
  mv_ff_k<<<64, 256, 0, stream>>>(cF, cB, dcW, cdec, dtf);
  proj1_k<<<64, 256, 0, stream>>>(hd0, sm, W1, b1, zbuf, dtf);
  proj2_k<<<32, 256, 0, stream>>>(zbuf, W2, emb, 0, xdec, nullptr, -1, dtf);

  unsigned short* hcur = hd0;
  unsigned short* hnxt = hd1;
  for (int i = 0; i < TG; ++i) {
    dec_step_k<<<32, 256, 0, stream>>>(xdec, hcur, hnxt, cdec, pk_dx, pk_dh, db,
                                       d_out, i, dtf);
    query_k<<<64, 256, 0, stream>>>(hnxt, wq, query, dtf);
    score_k<<<256, 256, 0, stream>>>(query, att, scoreb);
    softmax_k<<<32, 256, 0, stream>>>(scoreb, art_lens, probs);
    context_k<<<64, 256, 0, stream>>>(probs, att, ctx);
    proj1_k<<<64, 256, 0, stream>>>(hnxt, ctx, W1, b1, zbuf, dtf);
    proj2_k<<<32, 256, 0, stream>>>(zbuf, W2, emb, i + 1, xdec, d_out, i, dtf);
    unsigned short* tmp = hcur; hcur = hnxt; hnxt = tmp;
  }
}